// Round 4
// baseline (304.999 us; speedup 1.0000x reference)
//
#include <hip/hip_runtime.h>
#include <hip/hip_bf16.h>

#define D_MODEL 96
#define D_INNER 192
#define BATCH 32
#define HH 56
#define WW 56
#define NPIX (BATCH*HH*WW)   // 100352
#define LN_EPS 1e-5f

typedef unsigned short ushort_t;
typedef __attribute__((ext_vector_type(8))) short short8;   // 8 bf16 (4 VGPRs)
typedef __attribute__((ext_vector_type(4))) float f32x4;

// conv weights transposed to [tap][oc][ic] bf16 (331 KB) and
// in_proj live-half transposed to [oc=192][ic=96] bf16 (36.9 KB), module .data.
__device__ ushort_t g_Wt[9 * 96 * 192];
__device__ ushort_t g_Wit[192 * 96];

// round-to-nearest-even f32 -> bf16
static __device__ __forceinline__ unsigned short f2bf(float f) {
    unsigned u = __float_as_uint(f);
    unsigned r = (u + 0x7fffu + ((u >> 16) & 1u)) >> 16;
    return (unsigned short)r;
}

// ---------------------------------------------------------------------------
// Kernel 0: weight prep.
//  g_Wt[tap][oc][ic]  <- Wc[(tap*192+ic)*96+oc]          (conv, 165888 elems)
//  g_Wit[oc][ic]      <- Wi[ic*384 + oc], oc<192          (in_proj, 18432 elems)
// ---------------------------------------------------------------------------
__global__ __launch_bounds__(256) void k0_wt(const float* __restrict__ Wc,
                                             const float* __restrict__ Wi) {
    const int o = blockIdx.x * 256 + threadIdx.x;
    if (o < 9 * 96 * 192) {
        const int tap = o / (96 * 192);
        const int rem = o - tap * 96 * 192;
        const int oc = rem / 192;
        const int ic = rem - oc * 192;
        g_Wt[o] = f2bf(Wc[(tap * 192 + ic) * 96 + oc]);
    }
    if (o < 192 * 96) {
        const int oc = o / 96, ic = o - oc * 96;
        g_Wit[o] = f2bf(Wi[ic * 384 + oc]);
    }
}

// ---------------------------------------------------------------------------
// Kernel 1: LayerNorm + in_projection (96 -> live 192) via bf16 MFMA.
// Block = 256 thr (4 waves), 64 pixels. LN output staged bf16 in LDS.
// GEMM operand-swapped: A = Wit (M=oc), B = h (N=pixel) so D needs no
// transpose: lane holds pixel = lane&15, oc = mt*16 + (lane>>4)*4 + r.
// ---------------------------------------------------------------------------
__global__ __launch_bounds__(256) void k1_ln_proj(
    const float* __restrict__ X, const float* __restrict__ ln_w,
    const float* __restrict__ ln_b, const float* __restrict__ b_in,
    ushort_t* __restrict__ X1)
{
    __shared__ ushort_t sH[64 * 104];   // 13.3 KB, pixel stride 104 shorts
    const int t = threadIdx.x;

    // ---- LayerNorm: 4 threads per pixel ----
    const int g = t >> 2, tig = t & 3;
    const int pix = blockIdx.x * 64 + g;
    const float* xp = X + (size_t)pix * 96;
    float xv[24];
    float s = 0.f;
    #pragma unroll
    for (int k = 0; k < 24; ++k) { xv[k] = xp[tig + 4 * k]; s += xv[k]; }
    s += __shfl_xor(s, 1, 4);
    s += __shfl_xor(s, 2, 4);
    const float mu = s * (1.f / 96.f);
    float v = 0.f;
    #pragma unroll
    for (int k = 0; k < 24; ++k) { float d = xv[k] - mu; v += d * d; }
    v += __shfl_xor(v, 1, 4);
    v += __shfl_xor(v, 2, 4);
    const float rs = rsqrtf(v * (1.f / 96.f) + LN_EPS);
    #pragma unroll
    for (int k = 0; k < 24; ++k) {
        const int c = tig + 4 * k;
        sH[g * 104 + c] = f2bf((xv[k] - mu) * rs * ln_w[c] + ln_b[c]);
    }
    __syncthreads();

    // ---- MFMA GEMM: wave w -> pixels w*16..w*16+15, all 192 oc ----
    const int w = t >> 6, l = t & 63;
    const int lm = l & 15, lq = l >> 4;
    const ushort_t* hp = &sH[(w * 16 + lm) * 104 + lq * 8];

    f32x4 acc[12];
    const f32x4 zf = {0.f, 0.f, 0.f, 0.f};
    #pragma unroll
    for (int mt = 0; mt < 12; ++mt) acc[mt] = zf;

    #pragma unroll
    for (int kk = 0; kk < 3; ++kk) {
        const short8 hb = *(const short8*)(hp + kk * 32);
        #pragma unroll
        for (int mt = 0; mt < 12; ++mt) {
            const short8 wa = *(const short8*)(g_Wit + (mt * 16 + lm) * 96 + kk * 32 + lq * 8);
            acc[mt] = __builtin_amdgcn_mfma_f32_16x16x32_bf16(wa, hb, acc[mt], 0, 0, 0);
        }
    }

    // ---- pack 4 consecutive oc as bf16x4, store uint2 to pixel-major X1 ----
    const int p = blockIdx.x * 64 + w * 16 + lm;
    #pragma unroll
    for (int mt = 0; mt < 12; ++mt) {
        const int oc0 = mt * 16 + lq * 4;
        const float4 bv = *(const float4*)(b_in + oc0);
        uint2 u;
        u.x = (unsigned)f2bf(acc[mt][0] + bv.x) | ((unsigned)f2bf(acc[mt][1] + bv.y) << 16);
        u.y = (unsigned)f2bf(acc[mt][2] + bv.z) | ((unsigned)f2bf(acc[mt][3] + bv.w) << 16);
        *(uint2*)(X1 + (size_t)p * 192 + oc0) = u;
    }
}

// ---------------------------------------------------------------------------
// Kernel 2: 3x3 conv (192 -> 96) MFMA + bias + SiLU + residual.
// Block = 256 thr (4 waves), 8x8 output tile, halo 10x10x192 bf16 in LDS
// (pixel stride padded to 200 shorts -> 40,000 B -> 4 blocks/CU).
// Wave w: 16 pixels (w*16+lane&15) x all 96 oc; A from LDS (1 ds_read_b128
// per 6 MFMA), B from g_Wt via L1/L2 (shared across the 4 waves).
// ---------------------------------------------------------------------------
__global__ __launch_bounds__(256) void k2_conv_mfma(
    const ushort_t* __restrict__ X1, const float* __restrict__ conv_b,
    const float* __restrict__ X, float* __restrict__ OUT)
{
    __shared__ ushort_t sX[100 * 200];   // 40,000 B
    const int t = threadIdx.x;
    const int img = blockIdx.x / 49, tile = blockIdx.x % 49;
    const int ty = (tile / 7) * 8, tx = (tile % 7) * 8;

    // ---- stage halo tile (zero-pad at borders) ----
    for (int idx = t; idx < 2400; idx += 256) {        // 100 px * 24 uint4
        const int pix = idx / 24, q = idx % 24;
        const int prow = pix / 10, pcol = pix % 10;
        const int gr = ty + prow - 1, gc = tx + pcol - 1;
        uint4 val = make_uint4(0u, 0u, 0u, 0u);
        if (gr >= 0 && gr < HH && gc >= 0 && gc < WW)
            val = *(const uint4*)(X1 + ((size_t)((img * HH + gr) * WW + gc)) * 192 + q * 8);
        *(uint4*)&sX[pix * 200 + q * 8] = val;
    }
    __syncthreads();

    const int w = t >> 6, l = t & 63;
    const int lm = l & 15, lq = l >> 4;
    const int px_t = w * 16 + lm;            // A-row pixel within tile
    const int pr = px_t >> 3, pc = px_t & 7;

    f32x4 acc[6];
    const f32x4 zf = {0.f, 0.f, 0.f, 0.f};
    #pragma unroll
    for (int n = 0; n < 6; ++n) acc[n] = zf;

    #pragma unroll 1
    for (int ky = 0; ky < 3; ++ky) {
        #pragma unroll 1
        for (int kx = 0; kx < 3; ++kx) {
            const ushort_t* ap = &sX[((pr + ky) * 10 + (pc + kx)) * 200 + lq * 8];
            const ushort_t* bbase = g_Wt + (size_t)(ky * 3 + kx) * 96 * 192 + lm * 192 + lq * 8;
            #pragma unroll
            for (int kk = 0; kk < 6; ++kk) {
                const short8 a = *(const short8*)(ap + kk * 32);
                short8 b[6];
                #pragma unroll
                for (int n = 0; n < 6; ++n)
                    b[n] = *(const short8*)(bbase + n * 16 * 192 + kk * 32);
                #pragma unroll
                for (int n = 0; n < 6; ++n)
                    acc[n] = __builtin_amdgcn_mfma_f32_16x16x32_bf16(a, b[n], acc[n], 0, 0, 0);
            }
        }
    }

    // ---- D: col=lane&15 -> oc, row -> pixel w*16 + lq*4 + r4 ----
    #pragma unroll
    for (int n = 0; n < 6; ++n) {
        const int oc = n * 16 + lm;
        const float bv = conv_b[oc];
        #pragma unroll
        for (int r4 = 0; r4 < 4; ++r4) {
            const int p2 = w * 16 + lq * 4 + r4;
            const int grow = ty + (p2 >> 3), gcol = tx + (p2 & 7);
            const size_t o = ((size_t)((img * HH + grow) * WW + gcol)) * 96 + oc;
            const float y = acc[n][r4] + bv;
            const float sig = 1.f / (1.f + __expf(-y));
            OUT[o] = X[o] + y * sig;
        }
    }
}

extern "C" void kernel_launch(void* const* d_in, const int* in_sizes, int n_in,
                              void* d_out, int out_size, void* d_ws, size_t ws_size,
                              hipStream_t stream) {
    (void)in_sizes; (void)n_in; (void)out_size; (void)ws_size;
    const float* X    = (const float*)d_in[0];
    const float* ln_w = (const float*)d_in[1];
    const float* ln_b = (const float*)d_in[2];
    const float* Wi   = (const float*)d_in[3];
    const float* b_in = (const float*)d_in[4];
    const float* Wc   = (const float*)d_in[5];
    const float* cb   = (const float*)d_in[6];
    float* OUT = (float*)d_out;
    ushort_t* X1 = (ushort_t*)d_ws;   // 100352*192 bf16 = 38.5 MB

    k0_wt<<<(9 * 96 * 192 + 255) / 256, 256, 0, stream>>>(Wc, Wi);
    k1_ln_proj<<<NPIX / 64, 256, 0, stream>>>(X, ln_w, ln_b, b_in, X1);
    k2_conv_mfma<<<NPIX / 64, 256, 0, stream>>>(X1, cb, X, OUT);
}

// Round 6
// 151.683 us; speedup vs baseline: 2.0108x; 2.0108x over previous
//
#include <hip/hip_runtime.h>
#include <hip/hip_bf16.h>

#define D_MODEL 96
#define D_INNER 192
#define BATCH 32
#define HH 56
#define WW 56
#define NPIX (BATCH*HH*WW)   // 100352
#define LN_EPS 1e-5f
#define TAPS 18432           // shorts per tap slab (96 oc * 192 ic)
#define TAPBYTES 36864

typedef unsigned short ushort_t;
typedef __attribute__((ext_vector_type(8))) short short8;   // 8 bf16 (4 VGPRs)
typedef __attribute__((ext_vector_type(4))) float f32x4;

// conv weights transposed to [tap][oc][ic] bf16 (331 KB) and
// in_proj live-half transposed to [oc=192][ic=96] bf16 (36.9 KB), module .data.
__device__ __align__(16) ushort_t g_Wt[9 * 96 * 192];
__device__ __align__(16) ushort_t g_Wit[192 * 96];

// round-to-nearest-even f32 -> bf16
static __device__ __forceinline__ unsigned short f2bf(float f) {
    unsigned u = __float_as_uint(f);
    unsigned r = (u + 0x7fffu + ((u >> 16) & 1u)) >> 16;
    return (unsigned short)r;
}

// ---------------------------------------------------------------------------
// Kernel 0: weight prep.
//  g_Wt[tap][oc][ic]  <- Wc[(tap*192+ic)*96+oc]          (conv, 165888 elems)
//  g_Wit[oc][ic]      <- Wi[ic*384 + oc], oc<192          (in_proj, 18432 elems)
// ---------------------------------------------------------------------------
__global__ __launch_bounds__(256) void k0_wt(const float* __restrict__ Wc,
                                             const float* __restrict__ Wi) {
    const int o = blockIdx.x * 256 + threadIdx.x;
    if (o < 9 * 96 * 192) {
        const int tap = o / (96 * 192);
        const int rem = o - tap * 96 * 192;
        const int oc = rem / 192;
        const int ic = rem - oc * 192;
        g_Wt[o] = f2bf(Wc[(tap * 192 + ic) * 96 + oc]);
    }
    if (o < 192 * 96) {
        const int oc = o / 96, ic = o - oc * 96;
        g_Wit[o] = f2bf(Wi[ic * 384 + oc]);
    }
}

// ---------------------------------------------------------------------------
// Kernel 1: LayerNorm + in_projection (96 -> live 192) via bf16 MFMA.
// EXACT round-4 version (verified passing). Block = 256 thr (4 waves),
// 64 pixels; LN output staged bf16 in LDS; operand-swapped GEMM so D lands
// pixel-major; Wit fragments read direct from global (L2-resident).
// ---------------------------------------------------------------------------
__global__ __launch_bounds__(256) void k1_ln_proj(
    const float* __restrict__ X, const float* __restrict__ ln_w,
    const float* __restrict__ ln_b, const float* __restrict__ b_in,
    ushort_t* __restrict__ X1)
{
    __shared__ ushort_t sH[64 * 104];   // 13.3 KB, pixel stride 104 shorts
    const int t = threadIdx.x;

    // ---- LayerNorm: 4 threads per pixel ----
    const int g = t >> 2, tig = t & 3;
    const int pix = blockIdx.x * 64 + g;
    const float* xp = X + (size_t)pix * 96;
    float xv[24];
    float s = 0.f;
    #pragma unroll
    for (int k = 0; k < 24; ++k) { xv[k] = xp[tig + 4 * k]; s += xv[k]; }
    s += __shfl_xor(s, 1, 4);
    s += __shfl_xor(s, 2, 4);
    const float mu = s * (1.f / 96.f);
    float v = 0.f;
    #pragma unroll
    for (int k = 0; k < 24; ++k) { float d = xv[k] - mu; v += d * d; }
    v += __shfl_xor(v, 1, 4);
    v += __shfl_xor(v, 2, 4);
    const float rs = rsqrtf(v * (1.f / 96.f) + LN_EPS);
    #pragma unroll
    for (int k = 0; k < 24; ++k) {
        const int c = tig + 4 * k;
        sH[g * 104 + c] = f2bf((xv[k] - mu) * rs * ln_w[c] + ln_b[c]);
    }
    __syncthreads();

    // ---- MFMA GEMM: wave w -> pixels w*16..w*16+15, all 192 oc ----
    const int w = t >> 6, l = t & 63;
    const int lm = l & 15, lq = l >> 4;
    const ushort_t* hp = &sH[(w * 16 + lm) * 104 + lq * 8];

    f32x4 acc[12];
    const f32x4 zf = {0.f, 0.f, 0.f, 0.f};
    #pragma unroll
    for (int mt = 0; mt < 12; ++mt) acc[mt] = zf;

    #pragma unroll
    for (int kk = 0; kk < 3; ++kk) {
        const short8 hb = *(const short8*)(hp + kk * 32);
        #pragma unroll
        for (int mt = 0; mt < 12; ++mt) {
            const short8 wa = *(const short8*)(g_Wit + (mt * 16 + lm) * 96 + kk * 32 + lq * 8);
            acc[mt] = __builtin_amdgcn_mfma_f32_16x16x32_bf16(wa, hb, acc[mt], 0, 0, 0);
        }
    }

    // ---- pack 4 consecutive oc as bf16x4, store uint2 to pixel-major X1 ----
    const int p = blockIdx.x * 64 + w * 16 + lm;
    #pragma unroll
    for (int mt = 0; mt < 12; ++mt) {
        const int oc0 = mt * 16 + lq * 4;
        const float4 bv = *(const float4*)(b_in + oc0);
        uint2 u;
        u.x = (unsigned)f2bf(acc[mt][0] + bv.x) | ((unsigned)f2bf(acc[mt][1] + bv.y) << 16);
        u.y = (unsigned)f2bf(acc[mt][2] + bv.z) | ((unsigned)f2bf(acc[mt][3] + bv.w) << 16);
        *(uint2*)(X1 + (size_t)p * 192 + oc0) = u;
    }
}

// ---------------------------------------------------------------------------
// Kernel 2: 3x3 conv (192 -> 96) MFMA + bias + SiLU + residual.
// Block = 256 thr (4 waves), 256 px; wave = 64 px (4 m-tiles) x all 96 oc.
// Weights staged per-tap in LDS, double-buffered, via REGISTERS + ds_write
// (m201 stage_rc): global reads linear/coalesced (lane l reads 16 B at D),
// LDS write at D ^ key(row(D)), reads at A ^ key(row(A)) — same involution
// both sides (rows are 384 B = 3 x 128-B blocks; XOR of bits 4-6 never
// crosses a block, so row(A^key)==row(A)). T14 split: global loads issued
// before the MFMA phase, ds_write after, one barrier per tap.
// ---------------------------------------------------------------------------
__global__ __launch_bounds__(256, 2) void k2_conv_mfma(
    const ushort_t* __restrict__ X1, const float* __restrict__ conv_b,
    const float* __restrict__ X, float* __restrict__ OUT)
{
    __shared__ ushort_t sW[2][TAPS];   // 73,728 B -> 2 blocks/CU
    const int t = threadIdx.x;
    const int w = t >> 6, l = t & 63;
    const int lm = l & 15, lq = l >> 4;

    // ---- per-wave pixel geometry: 64 linear px, never crosses an image ----
    const int P0 = blockIdx.x * 256 + w * 64;
    const int img = P0 / 3136;
    const int ploc0 = P0 - img * 3136;
    int rr[4], cc[4];
    #pragma unroll
    for (int i = 0; i < 4; ++i) {
        const int pl = ploc0 + i * 16 + lm;
        rr[i] = pl / 56;
        cc[i] = pl - rr[i] * 56;
    }
    const size_t imgbase = (size_t)img * 3136 * 192;

    // staging geometry: wave w covers bytes [w*9216, (w+1)*9216) of the slab,
    // lane l the 16-B chunk at D = w*9216 + j*1024 + l*16.
    const int sbase = w * 9216 + l * 16;

    f32x4 acc[4][6];
    const f32x4 zf = {0.f, 0.f, 0.f, 0.f};
    #pragma unroll
    for (int i = 0; i < 4; ++i)
        #pragma unroll
        for (int n = 0; n < 6; ++n) acc[i][n] = zf;

    const short8 zero8 = {0, 0, 0, 0, 0, 0, 0, 0};
    const int bkey = (lm & 7) << 4;
    const int bbase0 = lm * 384 + lq * 16;   // logical byte offset in tap slab

    // ---- prologue: stage tap 0 into buf 0 ----
    uint4 r[9];
    #pragma unroll
    for (int j = 0; j < 9; ++j)
        r[j] = *(const uint4*)((const char*)g_Wt + sbase + j * 1024);
    #pragma unroll
    for (int j = 0; j < 9; ++j) {
        const int D = sbase + j * 1024;
        *(uint4*)((char*)&sW[0][0] + (D ^ (((D / 384) & 7) << 4))) = r[j];
    }
    __syncthreads();

    #pragma unroll 1
    for (int tap = 0; tap < 9; ++tap) {
        // issue next tap's global loads early (latency hides under MFMA)
        if (tap < 8) {
            const char* gsrc = (const char*)g_Wt + (size_t)(tap + 1) * TAPBYTES;
            #pragma unroll
            for (int j = 0; j < 9; ++j)
                r[j] = *(const uint4*)(gsrc + sbase + j * 1024);
        }

        const int ky = tap / 3, kx = tap - (tap / 3) * 3;
        const ushort_t* abase[4];
        bool av[4];
        #pragma unroll
        for (int i = 0; i < 4; ++i) {
            const int gr = rr[i] + ky - 1, gc = cc[i] + kx - 1;
            av[i] = (gr >= 0) && (gr < HH) && (gc >= 0) && (gc < WW);
            abase[i] = X1 + imgbase + (size_t)(gr * WW + gc) * 192 + lq * 8;
        }
        const char* bufp = (const char*)&sW[tap & 1][0];

        #pragma unroll
        for (int kk = 0; kk < 6; ++kk) {
            short8 b[6];
            #pragma unroll
            for (int n = 0; n < 6; ++n) {
                const int A = bbase0 + n * 6144 + kk * 64;   // n*16*384 B
                b[n] = *(const short8*)(bufp + (A ^ bkey));
            }
            short8 a[4];
            #pragma unroll
            for (int i = 0; i < 4; ++i)
                a[i] = av[i] ? *(const short8*)(abase[i] + kk * 32) : zero8;
            #pragma unroll
            for (int i = 0; i < 4; ++i)
                #pragma unroll
                for (int n = 0; n < 6; ++n)
                    acc[i][n] = __builtin_amdgcn_mfma_f32_16x16x32_bf16(
                        a[i], b[n], acc[i][n], 0, 0, 0);
        }

        // write next tap's slab (other buffer; its old readers synced at tap-1)
        if (tap < 8) {
            char* dst = (char*)&sW[(tap + 1) & 1][0];
            #pragma unroll
            for (int j = 0; j < 9; ++j) {
                const int D = sbase + j * 1024;
                *(uint4*)(dst + (D ^ (((D / 384) & 7) << 4))) = r[j];
            }
        }
        __syncthreads();
    }

    // ---- D: col=lane&15 -> oc, row -> pixel i*16 + lq*4 + r4 ----
    #pragma unroll
    for (int n = 0; n < 6; ++n) {
        const int oc = n * 16 + lm;
        const float bv = conv_b[oc];
        #pragma unroll
        for (int i = 0; i < 4; ++i) {
            #pragma unroll
            for (int r4 = 0; r4 < 4; ++r4) {
                const int p = P0 + i * 16 + lq * 4 + r4;
                const size_t o = (size_t)p * 96 + oc;
                const float y = acc[i][n][r4] + bv;
                const float sig = 1.f / (1.f + __expf(-y));
                OUT[o] = X[o] + y * sig;
            }
        }
    }
}

extern "C" void kernel_launch(void* const* d_in, const int* in_sizes, int n_in,
                              void* d_out, int out_size, void* d_ws, size_t ws_size,
                              hipStream_t stream) {
    (void)in_sizes; (void)n_in; (void)out_size; (void)ws_size;
    const float* X    = (const float*)d_in[0];
    const float* ln_w = (const float*)d_in[1];
    const float* ln_b = (const float*)d_in[2];
    const float* Wi   = (const float*)d_in[3];
    const float* b_in = (const float*)d_in[4];
    const float* Wc   = (const float*)d_in[5];
    const float* cb   = (const float*)d_in[6];
    float* OUT = (float*)d_out;
    ushort_t* X1 = (ushort_t*)d_ws;   // 100352*192 bf16 = 38.5 MB

    k0_wt<<<(9 * 96 * 192 + 255) / 256, 256, 0, stream>>>(Wc, Wi);
    k1_ln_proj<<<NPIX / 64, 256, 0, stream>>>(X, ln_w, ln_b, b_in, X1);
    k2_conv_mfma<<<NPIX / 256, 256, 0, stream>>>(X1, cb, X, OUT);
}